// Round 8
// baseline (636.643 us; speedup 1.0000x reference)
//
#include <hip/hip_runtime.h>

// Problem constants
#define NB     64      // batch
#define TT     2048    // time
#define INQ    8       // input size
#define CC     2       // channels
#define MM     10      // hidden m
#define ROWP   12      // padded row floats (48 B)
#define MATS   124     // matrix stride in tree buffer (124%32=28 -> lvl1 8-way not 16-way)
#define SKSTR  12      // sktri row stride floats (quad lanes 2-way banks = free)
#define SLEN   4       // sequential steps per quad segment
#define SEGS   64      // segments per block (256 thr / 4 lanes)
#define CSTEPS (SEGS*SLEN) // 256 steps per block
#define NCHUNK 8       // chunks per chain -> grid 1024 = exactly 4 blocks/CU at 128 VGPR
#define NCHAIN (NB*CC)
#define KTAY   6       // Taylor order (||G||^7/5040 ~1e-7/step << bf16 floor)

// Upper-triangle index for (k,j), k<j, into 45-element array
__device__ __forceinline__ constexpr int triIdx(int k, int j) {
    return k * 10 + j - ((k + 1) * (k + 2)) / 2;
}

// Broadcast lane (quad base + SRC)'s value to all 4 lanes of the quad.
template <int SRC>
__device__ __forceinline__ float dpp_qbcast(float v) {
    const int i = __float_as_int(v);
    const int r = __builtin_amdgcn_update_dpp(i, i, SRC * 0x55, 0xF, 0xF, true);
    return __int_as_float(r);
}

// One block per (chain, chunk). Quad owns a segment of SLEN sequential steps,
// rows split 3/3/2/2 so the Taylor live set fits a 128-VGPR budget with no
// hot spills. launch_bounds(256,4) caps VGPR at 128 -> 4 waves/SIMD; grid
// 1024 = exactly 4 blocks/CU, one balanced dispatch round (r7: 3 waves/SIMD,
// VALUBusy 52%, latency-exposed). Taylor uses UNNORMALIZED Acc_j = R*G^j
// with R += (1/j!)Acc_j (compile-time 1/j!): kills per-jt inv-muls and the
// Acc-init movs; first-k init kills the tr zero-movs. KTAY=6.
__global__ __launch_bounds__(256, 4)
void dev_serial(const float* __restrict__ x,
                const float* __restrict__ A,
                float* __restrict__ ws)
{
    __shared__ __align__(16) float sk_s[48 * SKSTR];    // 2304 B (rows >=45 zero)
    __shared__ __align__(16) float buf_s[SEGS * MATS];  // 31744 B tree buffer

    const int tid   = threadIdx.x;
    const int chain = blockIdx.x >> 3;   // / NCHUNK
    const int chunk = blockIdx.x & 7;
    const int n     = chain >> 1;        // / CC
    const int c     = chain & 1;

    // Precompute sktri[t][ip] = A[c][ip][k][j] - A[c][ip][j][k], t <-> (k<j)
    for (int e = tid; e < 48 * INQ; e += 256) {
        const int t  = e >> 3;
        const int ip = e & 7;
        float v = 0.0f;
        if (t < 45) {
            int k = 0, rem = t;
            while (rem >= 9 - k) { rem -= (9 - k); ++k; }
            const int j = k + 1 + rem;
            const float* Ab = A + (size_t)(c * INQ + ip) * (MM * MM);
            v = Ab[k * MM + j] - Ab[j * MM + k];
        }
        sk_s[t * SKSTR + ip] = v;
    }
    // zero the 4-float pad of each row (read by float4 loads, must be defined)
    for (int t = tid; t < 48; t += 256) {
        sk_s[t * SKSTR + 8]  = 0.0f; sk_s[t * SKSTR + 9]  = 0.0f;
        sk_s[t * SKSTR + 10] = 0.0f; sk_s[t * SKSTR + 11] = 0.0f;
    }
    __syncthreads();

    const int seg = tid >> 2;
    const int q   = tid & 3;                       // lane within quad
    const int r0  = (q < 2) ? 3 * q : (q == 2 ? 6 : 8);
    const int rc  = (q < 2) ? 3 : 2;               // real rows owned

    // Running product rows (identity; dummy 3rd row on q>=2 lanes never stored)
    float R[3][MM];
    #pragma unroll
    for (int r = 0; r < 3; ++r) {
        const int gi = (r0 + r > 9) ? 9 : (r0 + r);
        #pragma unroll
        for (int j = 0; j < MM; ++j)
            R[r][j] = (j == gi) ? 1.0f : 0.0f;
    }

    const float* xb = x + (size_t)n * TT * INQ;
    const int t0 = chunk * CSTEPS + seg * SLEN;

    #pragma unroll 1
    for (int s = 0; s < SLEN; ++s) {
        // ta <= 2047 always (8*256 covers 2048 steps, last is the pad step);
        // tn clamps at 2047 -> dx=0 -> E=I for the single pad step.
        const int ta = t0 + s;
        int tn = ta + 1; if (tn > TT - 1) tn = TT - 1;
        const float4* xpa = reinterpret_cast<const float4*>(xb + (size_t)ta * INQ);
        const float4* xpb = reinterpret_cast<const float4*>(xb + (size_t)tn * INQ);
        const float4 a0 = xpa[0], a1 = xpa[1];
        const float4 b0 = xpb[0], b1 = xpb[1];
        float dx[INQ];
        dx[0] = b0.x - a0.x; dx[1] = b0.y - a0.y; dx[2] = b0.z - a0.z; dx[3] = b0.w - a0.w;
        dx[4] = b1.x - a1.x; dx[5] = b1.y - a1.y; dx[6] = b1.z - a1.z; dx[7] = b1.w - a1.w;

        // My 12 tri values: tv[u] = sum_ip dx[ip] * sktri[q*12+u][ip]
        float tv[12];
        #pragma unroll
        for (int u = 0; u < 12; ++u) {
            const float4* sp = reinterpret_cast<const float4*>(&sk_s[(q * 12 + u) * SKSTR]);
            const float4 s0 = sp[0], s1 = sp[1];
            tv[u] = dx[0] * s0.x + dx[1] * s0.y + dx[2] * s0.z + dx[3] * s0.w
                  + dx[4] * s1.x + dx[5] * s1.y + dx[6] * s1.z + dx[7] * s1.w;
        }

        // Assemble full Tri[45] per-lane via DPP quad broadcast:
        // global tri index U was computed by quad-lane U/12 at tv[U%12].
        float Tri[45];
        #define TRIFILL(U) Tri[U] = dpp_qbcast<(U) / 12>(tv[(U) % 12]);
        TRIFILL(0)  TRIFILL(1)  TRIFILL(2)  TRIFILL(3)  TRIFILL(4)
        TRIFILL(5)  TRIFILL(6)  TRIFILL(7)  TRIFILL(8)  TRIFILL(9)
        TRIFILL(10) TRIFILL(11) TRIFILL(12) TRIFILL(13) TRIFILL(14)
        TRIFILL(15) TRIFILL(16) TRIFILL(17) TRIFILL(18) TRIFILL(19)
        TRIFILL(20) TRIFILL(21) TRIFILL(22) TRIFILL(23) TRIFILL(24)
        TRIFILL(25) TRIFILL(26) TRIFILL(27) TRIFILL(28) TRIFILL(29)
        TRIFILL(30) TRIFILL(31) TRIFILL(32) TRIFILL(33) TRIFILL(34)
        TRIFILL(35) TRIFILL(36) TRIFILL(37) TRIFILL(38) TRIFILL(39)
        TRIFILL(40) TRIFILL(41) TRIFILL(42) TRIFILL(43) TRIFILL(44)
        #undef TRIFILL

        // G[k][j] = +Tri[triIdx(k,j)] (k<j), -Tri[triIdx(j,k)] (k>j), 0 diag.
        // tr = Src * G, with first-contributing-k as the init (no zero-movs).
        float Acc[3][MM];

        #define TAYLOR_TERM(SRC, CJ)                                          \
        {                                                                     \
            _Pragma("unroll")                                                 \
            for (int r = 0; r < 3; ++r) {                                     \
                float tr[MM];                                                 \
                /* init: j==0 <- k=1 (sign -); j>=1 <- k=0 (sign +) */        \
                tr[0] = -SRC[r][1] * Tri[triIdx(0, 1)];                       \
                _Pragma("unroll")                                             \
                for (int j = 1; j < MM; ++j)                                  \
                    tr[j] = SRC[r][0] * Tri[triIdx(0, j)];                    \
                _Pragma("unroll")                                             \
                for (int k = 1; k < MM; ++k) {                                \
                    const float av = SRC[r][k];                               \
                    _Pragma("unroll")                                         \
                    for (int j = 0; j < MM; ++j) {                            \
                        if (k == j) continue;                                 \
                        if (j == 0 && k == 1) continue;                       \
                        if (j > k)      tr[j] += av * Tri[triIdx(k, j)];      \
                        else            tr[j] -= av * Tri[triIdx(j, k)];      \
                    }                                                         \
                }                                                             \
                _Pragma("unroll")                                             \
                for (int j = 0; j < MM; ++j) {                                \
                    Acc[r][j] = tr[j];                                        \
                    R[r][j]   = fmaf(CJ, tr[j], R[r][j]);                     \
                }                                                             \
            }                                                                 \
        }

        TAYLOR_TERM(R,   1.0f)                 // j=1
        TAYLOR_TERM(Acc, 0.5f)                 // j=2
        TAYLOR_TERM(Acc, 0.16666667f)          // j=3
        TAYLOR_TERM(Acc, 0.041666668f)         // j=4
        TAYLOR_TERM(Acc, 0.0083333338f)        // j=5
        TAYLOR_TERM(Acc, 0.0013888889f)        // j=6
        #undef TAYLOR_TERM
    }

    // Store segment product (real rows only) into tree region
    {
        float* dst = &buf_s[seg * MATS];
        #pragma unroll
        for (int r = 0; r < 3; ++r) {
            if (r < rc) {
                float4* drow = reinterpret_cast<float4*>(dst + (r0 + r) * ROWP);
                drow[0] = make_float4(R[r][0], R[r][1], R[r][2], R[r][3]);
                drow[1] = make_float4(R[r][4], R[r][5], R[r][6], R[r][7]);
                drow[2] = make_float4(R[r][8], R[r][9], 0.0f, 0.0f);
            }
        }
    }
    __syncthreads();

    // Pair-style dyadic tree over 64 segment products (6 levels)
    #pragma unroll 1
    for (int span = 2; span <= SEGS; span <<= 1) {
        const int np = SEGS / span;
        if (tid < 2 * np) {
            const int pr = tid >> 1;
            const int pq = tid & 1;
            const int ls = pr * span;
            const int rs = ls + (span >> 1);

            float lrow[5][MM];
            #pragma unroll
            for (int r = 0; r < 5; ++r) {
                const float4* lr = reinterpret_cast<const float4*>(
                    &buf_s[ls * MATS + (pq * 5 + r) * ROWP]);
                const float4 a = lr[0], b = lr[1], c4 = lr[2];
                lrow[r][0] = a.x;  lrow[r][1] = a.y;  lrow[r][2] = a.z;  lrow[r][3] = a.w;
                lrow[r][4] = b.x;  lrow[r][5] = b.y;  lrow[r][6] = b.z;  lrow[r][7] = b.w;
                lrow[r][8] = c4.x; lrow[r][9] = c4.y;
            }

            float d[5][MM];
            #pragma unroll
            for (int r = 0; r < 5; ++r)
                #pragma unroll
                for (int j = 0; j < MM; ++j)
                    d[r][j] = 0.0f;

            #pragma unroll
            for (int k = 0; k < MM; ++k) {
                const float4* rr = reinterpret_cast<const float4*>(
                    &buf_s[rs * MATS + k * ROWP]);
                const float4 a = rr[0], b = rr[1], c4 = rr[2];
                float rrow[MM];
                rrow[0] = a.x;  rrow[1] = a.y;  rrow[2] = a.z;  rrow[3] = a.w;
                rrow[4] = b.x;  rrow[5] = b.y;  rrow[6] = b.z;  rrow[7] = b.w;
                rrow[8] = c4.x; rrow[9] = c4.y;
                #pragma unroll
                for (int r = 0; r < 5; ++r) {
                    const float lv = lrow[r][k];
                    #pragma unroll
                    for (int j = 0; j < MM; ++j)
                        d[r][j] += lv * rrow[j];
                }
            }

            float* dst = &buf_s[ls * MATS + pq * 5 * ROWP];
            #pragma unroll
            for (int r = 0; r < 5; ++r) {
                float4* drow = reinterpret_cast<float4*>(dst + r * ROWP);
                drow[0] = make_float4(d[r][0], d[r][1], d[r][2], d[r][3]);
                drow[1] = make_float4(d[r][4], d[r][5], d[r][6], d[r][7]);
                drow[2] = make_float4(d[r][8], d[r][9], 0.0f, 0.0f);
            }
        }
        __syncthreads();
    }

    // slot 0 = chunk product -> ws (unpadded 100 floats)
    if (tid < 100) {
        const int i = tid / 10;
        const int j = tid - i * 10;
        ws[((size_t)chain * NCHUNK + chunk) * 100 + tid] = buf_s[i * ROWP + j];
    }
}

// Combine NCHUNK chunk products per chain. One thread per (chain, row).
__global__ __launch_bounds__(256) void dev_combine(const float* __restrict__ ws,
                                                   float* __restrict__ out)
{
    const int id = blockIdx.x * 256 + threadIdx.x;
    if (id >= NCHAIN * MM) return;
    const int chain = id / MM;
    const int r     = id - chain * MM;

    const float* base = ws + (size_t)chain * NCHUNK * 100;
    float R[MM];
    #pragma unroll
    for (int j = 0; j < MM; ++j) R[j] = base[r * MM + j];

    #pragma unroll 1
    for (int ck = 1; ck < NCHUNK; ++ck) {
        const float* Mb = base + ck * 100;
        float Rn[MM];
        #pragma unroll
        for (int j = 0; j < MM; ++j) Rn[j] = 0.0f;
        #pragma unroll
        for (int k = 0; k < MM; ++k) {
            const float rv = R[k];
            #pragma unroll
            for (int j = 0; j < MM; ++j)
                Rn[j] += rv * Mb[k * MM + j];
        }
        #pragma unroll
        for (int j = 0; j < MM; ++j) R[j] = Rn[j];
    }

    #pragma unroll
    for (int j = 0; j < MM; ++j)
        out[(size_t)chain * 100 + r * MM + j] = R[j];
}

extern "C" void kernel_launch(void* const* d_in, const int* in_sizes, int n_in,
                              void* d_out, int out_size, void* d_ws, size_t ws_size,
                              hipStream_t stream) {
    (void)in_sizes; (void)n_in; (void)out_size; (void)ws_size;
    const float* x = (const float*)d_in[0];  // (64, 2048, 8)
    const float* A = (const float*)d_in[1];  // (2, 8, 10, 10)
    float* out = (float*)d_out;              // (64, 2, 10, 10)
    float* ws  = (float*)d_ws;               // 128*8*100 floats = 409600 B

    dev_serial<<<dim3(NCHAIN * NCHUNK), dim3(256), 0, stream>>>(x, A, ws);
    dev_combine<<<dim3((NCHAIN * MM + 255) / 256), dim3(256), 0, stream>>>(ws, out);
}

// Round 9
// 121.740 us; speedup vs baseline: 5.2295x; 5.2295x over previous
//
#include <hip/hip_runtime.h>

// Problem constants
#define NB     64      // batch
#define TT     2048    // time
#define INQ    8       // input size
#define CC     2       // channels
#define MM     10      // hidden m
#define ROWP   12      // padded row floats (48 B)
#define MATS   124     // matrix stride in LDS tree (124%32=28 -> lvl1 8-way max)
#define SKSTR  12      // sktri row stride floats (quad lanes 2-way banks = free)
#define SLEN   8       // sequential steps per quad segment
#define SEGS   64      // segments per block (256 thr / 4 lanes)
#define NCHUNK 4       // quarters per chain -> K1 grid 512 = exactly 2 blocks/CU
#define NCHAIN (NB*CC)

// Upper-triangle index for (k,j), k<j, into 45-element array
__device__ __forceinline__ constexpr int triIdx(int k, int j) {
    return k * 10 + j - ((k + 1) * (k + 2)) / 2;
}

// Broadcast lane (quad base + SRC)'s value to all 4 lanes of the quad.
template <int SRC>
__device__ __forceinline__ float dpp_qbcast(float v) {
    const int i = __float_as_int(v);
    const int r = __builtin_amdgcn_update_dpp(i, i, SRC * 0x55, 0xF, 0xF, true);
    return __int_as_float(r);
}

// K1: one block per (chain, quarter). Quad owns a segment of SLEN=8 steps;
// rows split 3/3/2/2 (Taylor live set R30+Acc30+Tri45+tr10 ~ fits the 136-VGPR
// no-spill point; plain launch_bounds(256) is the ONLY proven-good occupancy
// config — (256,2) and (256,4) both made the allocator spill, r4/r8).
// x loads are software-pipelined (cur/nxt) so the L2 latency of the step-s+1
// load hides under step-s's ~3.7k-cycle Taylor block. After the serial phase:
// 5 in-block tree levels (64 -> 2 products), write 2 padded mats to ws.
// Deep latency-bound levels + final combine live in K2 for clean profiling.
__global__ __launch_bounds__(256)
void dev_serial(const float* __restrict__ x,
                const float* __restrict__ A,
                float* __restrict__ ws)
{
    __shared__ __align__(16) float sk_s[48 * SKSTR];    // 2304 B (rows >=45 zero)
    __shared__ __align__(16) float buf_s[SEGS * MATS];  // 31744 B tree buffer

    const int tid   = threadIdx.x;
    const int chain = blockIdx.x >> 2;   // / NCHUNK
    const int qt    = blockIdx.x & 3;
    const int n     = chain >> 1;        // / CC
    const int c     = chain & 1;

    // Precompute sktri[t][ip] = A[c][ip][k][j] - A[c][ip][j][k], t <-> (k<j)
    for (int e = tid; e < 48 * INQ; e += 256) {
        const int t  = e >> 3;
        const int ip = e & 7;
        float v = 0.0f;
        if (t < 45) {
            int k = 0, rem = t;
            while (rem >= 9 - k) { rem -= (9 - k); ++k; }
            const int j = k + 1 + rem;
            const float* Ab = A + (size_t)(c * INQ + ip) * (MM * MM);
            v = Ab[k * MM + j] - Ab[j * MM + k];
        }
        sk_s[t * SKSTR + ip] = v;
    }
    for (int t = tid; t < 48; t += 256) {
        sk_s[t * SKSTR + 8]  = 0.0f; sk_s[t * SKSTR + 9]  = 0.0f;
        sk_s[t * SKSTR + 10] = 0.0f; sk_s[t * SKSTR + 11] = 0.0f;
    }
    __syncthreads();

    const int seg = tid >> 2;
    const int q   = tid & 3;                       // lane within quad
    const int r0  = (q < 2) ? 3 * q : (q == 2 ? 6 : 8);
    const int rc  = (q < 2) ? 3 : 2;               // real rows owned

    // Running product rows (identity; dummy 3rd row on q>=2 lanes never stored)
    float R[3][MM];
    #pragma unroll
    for (int r = 0; r < 3; ++r) {
        const int gi = (r0 + r > 9) ? 9 : (r0 + r);
        #pragma unroll
        for (int j = 0; j < MM; ++j)
            R[r][j] = (j == gi) ? 1.0f : 0.0f;
    }

    const float* xb = x + (size_t)n * TT * INQ;
    const int t0 = qt * (SEGS * SLEN) + seg * SLEN;   // max t0+7 = 2047: no ta clamp

    // Pipelined x: cur = x[t0], nxt = x[t0+1]
    float4 cur0, cur1, nxt0, nxt1;
    {
        const float4* p = reinterpret_cast<const float4*>(xb + (size_t)t0 * INQ);
        cur0 = p[0]; cur1 = p[1];
        int t1 = t0 + 1; if (t1 > TT - 1) t1 = TT - 1;
        const float4* pn = reinterpret_cast<const float4*>(xb + (size_t)t1 * INQ);
        nxt0 = pn[0]; nxt1 = pn[1];
    }

    #pragma unroll 1
    for (int s = 0; s < SLEN; ++s) {
        float dx[INQ];
        dx[0] = nxt0.x - cur0.x; dx[1] = nxt0.y - cur0.y;
        dx[2] = nxt0.z - cur0.z; dx[3] = nxt0.w - cur0.w;
        dx[4] = nxt1.x - cur1.x; dx[5] = nxt1.y - cur1.y;
        dx[6] = nxt1.z - cur1.z; dx[7] = nxt1.w - cur1.w;
        cur0 = nxt0; cur1 = nxt1;
        // issue load for step s+1 now; consumed next iteration (hides latency
        // under this step's Taylor block)
        {
            int t2 = t0 + s + 2; if (t2 > TT - 1) t2 = TT - 1;
            const float4* pn = reinterpret_cast<const float4*>(xb + (size_t)t2 * INQ);
            nxt0 = pn[0]; nxt1 = pn[1];
        }

        // My 12 tri values: tv[u] = sum_ip dx[ip] * sktri[q*12+u][ip]
        float tv[12];
        #pragma unroll
        for (int u = 0; u < 12; ++u) {
            const float4* sp = reinterpret_cast<const float4*>(&sk_s[(q * 12 + u) * SKSTR]);
            const float4 s0 = sp[0], s1 = sp[1];
            tv[u] = dx[0] * s0.x + dx[1] * s0.y + dx[2] * s0.z + dx[3] * s0.w
                  + dx[4] * s1.x + dx[5] * s1.y + dx[6] * s1.z + dx[7] * s1.w;
        }

        // Assemble full Tri[45] per-lane via DPP quad broadcast:
        // global tri index U was computed by quad-lane U/12 at tv[U%12].
        float Tri[45];
        #define TRIFILL(U) Tri[U] = dpp_qbcast<(U) / 12>(tv[(U) % 12]);
        TRIFILL(0)  TRIFILL(1)  TRIFILL(2)  TRIFILL(3)  TRIFILL(4)
        TRIFILL(5)  TRIFILL(6)  TRIFILL(7)  TRIFILL(8)  TRIFILL(9)
        TRIFILL(10) TRIFILL(11) TRIFILL(12) TRIFILL(13) TRIFILL(14)
        TRIFILL(15) TRIFILL(16) TRIFILL(17) TRIFILL(18) TRIFILL(19)
        TRIFILL(20) TRIFILL(21) TRIFILL(22) TRIFILL(23) TRIFILL(24)
        TRIFILL(25) TRIFILL(26) TRIFILL(27) TRIFILL(28) TRIFILL(29)
        TRIFILL(30) TRIFILL(31) TRIFILL(32) TRIFILL(33) TRIFILL(34)
        TRIFILL(35) TRIFILL(36) TRIFILL(37) TRIFILL(38) TRIFILL(39)
        TRIFILL(40) TRIFILL(41) TRIFILL(42) TRIFILL(43) TRIFILL(44)
        #undef TRIFILL

        // G[k][j] = +Tri[triIdx(k,j)] (k<j), -Tri[triIdx(j,k)] (k>j), 0 diag.
        // Unnormalized Horner: Acc_j = Src*G; R += (1/j!)*Acc_j (ascending).
        float Acc[3][MM];

        #define TAYLOR_TERM(SRC, CJ)                                          \
        {                                                                     \
            _Pragma("unroll")                                                 \
            for (int r = 0; r < 3; ++r) {                                     \
                float tr[MM];                                                 \
                tr[0] = -SRC[r][1] * Tri[triIdx(0, 1)];                       \
                _Pragma("unroll")                                             \
                for (int j = 1; j < MM; ++j)                                  \
                    tr[j] = SRC[r][0] * Tri[triIdx(0, j)];                    \
                _Pragma("unroll")                                             \
                for (int k = 1; k < MM; ++k) {                                \
                    const float av = SRC[r][k];                               \
                    _Pragma("unroll")                                         \
                    for (int j = 0; j < MM; ++j) {                            \
                        if (k == j) continue;                                 \
                        if (j == 0 && k == 1) continue;                       \
                        if (j > k)      tr[j] += av * Tri[triIdx(k, j)];      \
                        else            tr[j] -= av * Tri[triIdx(j, k)];      \
                    }                                                         \
                }                                                             \
                _Pragma("unroll")                                             \
                for (int j = 0; j < MM; ++j) {                                \
                    Acc[r][j] = tr[j];                                        \
                    R[r][j]   = fmaf(CJ, tr[j], R[r][j]);                     \
                }                                                             \
            }                                                                 \
        }

        TAYLOR_TERM(R,   1.0f)                 // j=1
        TAYLOR_TERM(Acc, 0.5f)                 // j=2
        TAYLOR_TERM(Acc, 0.16666667f)          // j=3
        TAYLOR_TERM(Acc, 0.041666668f)         // j=4
        TAYLOR_TERM(Acc, 0.0083333338f)        // j=5
        TAYLOR_TERM(Acc, 0.0013888889f)        // j=6
        #undef TAYLOR_TERM
    }

    // Store segment product (real rows only) into tree region
    {
        float* dst = &buf_s[seg * MATS];
        #pragma unroll
        for (int r = 0; r < 3; ++r) {
            if (r < rc) {
                float4* drow = reinterpret_cast<float4*>(dst + (r0 + r) * ROWP);
                drow[0] = make_float4(R[r][0], R[r][1], R[r][2], R[r][3]);
                drow[1] = make_float4(R[r][4], R[r][5], R[r][6], R[r][7]);
                drow[2] = make_float4(R[r][8], R[r][9], 0.0f, 0.0f);
            }
        }
    }
    __syncthreads();

    // Pair-style dyadic tree, 5 levels only (64 -> 2 products at slots 0, 32)
    #pragma unroll 1
    for (int span = 2; span <= 32; span <<= 1) {
        const int np = SEGS / span;
        if (tid < 2 * np) {
            const int pr = tid >> 1;
            const int pq = tid & 1;
            const int ls = pr * span;
            const int rs = ls + (span >> 1);

            float lrow[5][MM];
            #pragma unroll
            for (int r = 0; r < 5; ++r) {
                const float4* lr = reinterpret_cast<const float4*>(
                    &buf_s[ls * MATS + (pq * 5 + r) * ROWP]);
                const float4 a = lr[0], b = lr[1], c4 = lr[2];
                lrow[r][0] = a.x;  lrow[r][1] = a.y;  lrow[r][2] = a.z;  lrow[r][3] = a.w;
                lrow[r][4] = b.x;  lrow[r][5] = b.y;  lrow[r][6] = b.z;  lrow[r][7] = b.w;
                lrow[r][8] = c4.x; lrow[r][9] = c4.y;
            }

            float d[5][MM];
            #pragma unroll
            for (int r = 0; r < 5; ++r)
                #pragma unroll
                for (int j = 0; j < MM; ++j)
                    d[r][j] = 0.0f;

            #pragma unroll
            for (int k = 0; k < MM; ++k) {
                const float4* rr = reinterpret_cast<const float4*>(
                    &buf_s[rs * MATS + k * ROWP]);
                const float4 a = rr[0], b = rr[1], c4 = rr[2];
                float rrow[MM];
                rrow[0] = a.x;  rrow[1] = a.y;  rrow[2] = a.z;  rrow[3] = a.w;
                rrow[4] = b.x;  rrow[5] = b.y;  rrow[6] = b.z;  rrow[7] = b.w;
                rrow[8] = c4.x; rrow[9] = c4.y;
                #pragma unroll
                for (int r = 0; r < 5; ++r) {
                    const float lv = lrow[r][k];
                    #pragma unroll
                    for (int j = 0; j < MM; ++j)
                        d[r][j] += lv * rrow[j];
                }
            }

            float* dst = &buf_s[ls * MATS + pq * 5 * ROWP];
            #pragma unroll
            for (int r = 0; r < 5; ++r) {
                float4* drow = reinterpret_cast<float4*>(dst + r * ROWP);
                drow[0] = make_float4(d[r][0], d[r][1], d[r][2], d[r][3]);
                drow[1] = make_float4(d[r][4], d[r][5], d[r][6], d[r][7]);
                drow[2] = make_float4(d[r][8], d[r][9], 0.0f, 0.0f);
            }
        }
        __syncthreads();
    }

    // Write the 2 half-quarter products (slots 0 and 32), padded 120 floats
    // each, to ws[(chain*4+qt)*2 + m]. ws total: 1024 mats * 480 B = 480 KB.
    if (tid < 60) {
        const int m  = tid / 30;         // 0,1
        const int o4 = tid - m * 30;     // float4 index within padded matrix
        const float4 v = reinterpret_cast<const float4*>(&buf_s[(m * 32) * MATS])[o4];
        reinterpret_cast<float4*>(ws)[(((size_t)chain * 4 + qt) * 2 + m) * 30 + o4] = v;
    }
}

// K2: one block per chain; combine its 8 half-quarter products (time order)
// with a 3-level LDS tree, write the 10x10 result to out.
__global__ __launch_bounds__(256)
void dev_tree8(const float* __restrict__ ws, float* __restrict__ out)
{
    __shared__ __align__(16) float buf_s[8 * MATS];
    const int tid   = threadIdx.x;
    const int chain = blockIdx.x;

    if (tid < 240) {
        const int m  = tid / 30;
        const int o4 = tid - m * 30;
        const float4 v = reinterpret_cast<const float4*>(ws)[((size_t)chain * 8 + m) * 30 + o4];
        reinterpret_cast<float4*>(&buf_s[m * MATS])[o4] = v;
    }
    __syncthreads();

    #pragma unroll 1
    for (int span = 2; span <= 8; span <<= 1) {
        const int np = 8 / span;
        if (tid < 2 * np) {
            const int pr = tid >> 1;
            const int pq = tid & 1;
            const int ls = pr * span;
            const int rs = ls + (span >> 1);

            float lrow[5][MM];
            #pragma unroll
            for (int r = 0; r < 5; ++r) {
                const float4* lr = reinterpret_cast<const float4*>(
                    &buf_s[ls * MATS + (pq * 5 + r) * ROWP]);
                const float4 a = lr[0], b = lr[1], c4 = lr[2];
                lrow[r][0] = a.x;  lrow[r][1] = a.y;  lrow[r][2] = a.z;  lrow[r][3] = a.w;
                lrow[r][4] = b.x;  lrow[r][5] = b.y;  lrow[r][6] = b.z;  lrow[r][7] = b.w;
                lrow[r][8] = c4.x; lrow[r][9] = c4.y;
            }

            float d[5][MM];
            #pragma unroll
            for (int r = 0; r < 5; ++r)
                #pragma unroll
                for (int j = 0; j < MM; ++j)
                    d[r][j] = 0.0f;

            #pragma unroll
            for (int k = 0; k < MM; ++k) {
                const float4* rr = reinterpret_cast<const float4*>(
                    &buf_s[rs * MATS + k * ROWP]);
                const float4 a = rr[0], b = rr[1], c4 = rr[2];
                float rrow[MM];
                rrow[0] = a.x;  rrow[1] = a.y;  rrow[2] = a.z;  rrow[3] = a.w;
                rrow[4] = b.x;  rrow[5] = b.y;  rrow[6] = b.z;  rrow[7] = b.w;
                rrow[8] = c4.x; rrow[9] = c4.y;
                #pragma unroll
                for (int r = 0; r < 5; ++r) {
                    const float lv = lrow[r][k];
                    #pragma unroll
                    for (int j = 0; j < MM; ++j)
                        d[r][j] += lv * rrow[j];
                }
            }

            float* dst = &buf_s[ls * MATS + pq * 5 * ROWP];
            #pragma unroll
            for (int r = 0; r < 5; ++r) {
                float4* drow = reinterpret_cast<float4*>(dst + r * ROWP);
                drow[0] = make_float4(d[r][0], d[r][1], d[r][2], d[r][3]);
                drow[1] = make_float4(d[r][4], d[r][5], d[r][6], d[r][7]);
                drow[2] = make_float4(d[r][8], d[r][9], 0.0f, 0.0f);
            }
        }
        __syncthreads();
    }

    if (tid < 100) {
        const int i = tid / 10;
        const int j = tid - i * 10;
        out[(size_t)chain * 100 + tid] = buf_s[i * ROWP + j];
    }
}

extern "C" void kernel_launch(void* const* d_in, const int* in_sizes, int n_in,
                              void* d_out, int out_size, void* d_ws, size_t ws_size,
                              hipStream_t stream) {
    (void)in_sizes; (void)n_in; (void)out_size; (void)ws_size;
    const float* x = (const float*)d_in[0];  // (64, 2048, 8)
    const float* A = (const float*)d_in[1];  // (2, 8, 10, 10)
    float* out = (float*)d_out;              // (64, 2, 10, 10)
    float* ws  = (float*)d_ws;               // 1024 mats * 480 B = 491,520 B

    dev_serial<<<dim3(NCHAIN * NCHUNK), dim3(256), 0, stream>>>(x, A, ws);
    dev_tree8<<<dim3(NCHAIN), dim3(256), 0, stream>>>(ws, out);
}